// Round 9
// baseline (304.358 us; speedup 1.0000x reference)
//
#include <hip/hip_runtime.h>
#include <hip/hip_bf16.h>
#include <math.h>

// Cosine attention, n=8, L=S=2048, d=v=64.
// out0 = softmax((q^·k^T)/8) @ V  [8,2048,64]; out1 = softmax scores [8,2048,2048]
// |score| <= 1/8 (unit vectors) -> exp in [0.88,1.13] -> no running max needed.
//
// v9 = two-phase streaming-store version of the r8 kernel.
//   Diagnosis (r8): 99us vs ~35us byte-floor with VALU 12% / MFMA 3.3%; all
//   128MB of score stores burst in the terminal epilogue -> ~20us serialized
//   write drain per block round that overlaps nothing.
//   Phase 1 (mask-bound): QK -> exp -> rowsum only. Mask staged coalesced
//     through LDS (r8 scheme, proven); each owner lane PACKS its 64 mask bits
//     into 2 VGPRs -> mask read from HBM exactly once.
//   Phase 2 (write-bound, stores spread): recompute QK (2 extra MFMA/chunk at
//     3% MfmaUtil = free), exp from packed bits, e_lds exchange, FULL-RATE
//     16x16x32 PV, and a per-chunk coalesced normalized score store read
//     straight from e_lds (thread t -> row t>>5, cols (t&31)*4: 32 lanes =
//     512B contiguous). Stores spread over ~70% of the kernel.
//   r5 tried two-phase and lost 33us; its three bugs (64B-split stores,
//   half-rate 16x16x16 PV, XCD pinning thrash) are all absent here.
//   Keep: transposed QK, K ping-pong, bv dbuf prefetch (+1 chunk cover),
//   consumption-order issue, lgkm-only barriers, unpinned grid.
// Mask arrives as int32 (harness materializes bool as int) — NOT bytes.

typedef __bf16 bf16x8 __attribute__((ext_vector_type(8)));
typedef __bf16 bf16x4 __attribute__((ext_vector_type(4)));
typedef float f32x4 __attribute__((ext_vector_type(4)));

#define NB 8
#define LL 2048
#define SS 2048
#define DD 64

// ---- prep 1: L2-normalize Q (fold 1/8) and K rows, cast to bf16 ----
__global__ __launch_bounds__(256) void prep_norm(const float* __restrict__ q,
                                                 const float* __restrict__ k,
                                                 __bf16* __restrict__ Qb,
                                                 __bf16* __restrict__ Kb) {
  int w = threadIdx.x >> 6, lane = threadIdx.x & 63;
  int r = blockIdx.x * 4 + w;
  const float* src;
  __bf16* dst;
  float extra;
  if (r < NB * LL) {
    src = q + (size_t)r * DD;
    dst = Qb + (size_t)r * DD;
    extra = 0.125f;  // fold 1/sqrt(64) into Q
  } else {
    int rk = r - NB * LL;
    src = k + (size_t)rk * DD;
    dst = Kb + (size_t)rk * DD;
    extra = 1.0f;
  }
  float x = src[lane];
  float ss = x * x;
  ss += __shfl_xor(ss, 1);
  ss += __shfl_xor(ss, 2);
  ss += __shfl_xor(ss, 4);
  ss += __shfl_xor(ss, 8);
  ss += __shfl_xor(ss, 16);
  ss += __shfl_xor(ss, 32);
  float nrm = sqrtf(ss);
  float sc = extra / fmaxf(nrm, 1e-12f);
  dst[lane] = (__bf16)(x * sc);
}

// ---- prep 2: V [n][s][v] f32 -> Vt [n][v][s] bf16 (64x64 LDS tiles) ----
__global__ __launch_bounds__(256) void prep_vt(const float* __restrict__ v,
                                               __bf16* __restrict__ Vt) {
  __shared__ __bf16 tile[64][72];
  int n = blockIdx.y;
  int s0 = blockIdx.x * 64;
  int t = threadIdx.x;
#pragma unroll
  for (int it = 0; it < 4; ++it) {
    int idx = t + it * 256;
    int s = idx >> 4, c = idx & 15;
    float4 f = *(const float4*)(v + ((size_t)(n * SS + s0 + s)) * DD + c * 4);
    tile[s][c * 4 + 0] = (__bf16)f.x;
    tile[s][c * 4 + 1] = (__bf16)f.y;
    tile[s][c * 4 + 2] = (__bf16)f.z;
    tile[s][c * 4 + 3] = (__bf16)f.w;
  }
  __syncthreads();
#pragma unroll
  for (int it = 0; it < 4; ++it) {
    int idx = t + it * 256;
    int vv = idx >> 4, c = idx & 15;
    bf16x4 o;
    o[0] = tile[c * 4 + 0][vv];
    o[1] = tile[c * 4 + 1][vv];
    o[2] = tile[c * 4 + 2][vv];
    o[3] = tile[c * 4 + 3][vv];
    *(bf16x4*)(Vt + ((size_t)(n * DD + vv)) * SS + s0 + c * 4) = o;
  }
}

// ---- main: 16 L-rows per block, 8 waves (512 thr), two-phase S stream ----
// Wave w: QK for s-cols [w*16, w*16+16) of each 128-col chunk (transposed
// D[s][l]); per-lane: (l = l0+m16, s = sc + w*16 + quad*4 + r).
// PV split by (v-group = w&3, s-half = (w>>2)*64).
__global__ __launch_bounds__(512, 4) void attn_main(const __bf16* __restrict__ Qb,
                                                    const __bf16* __restrict__ Kb,
                                                    const __bf16* __restrict__ Vt,
                                                    const int* __restrict__ mask,
                                                    float* __restrict__ out_val,
                                                    float* __restrict__ out_score) {
  __shared__ __bf16 e_lds[2][16][136];     // E chunk, row = l, col = s-in-chunk
  __shared__ unsigned mb_lds[2][16][33];   // packed mask (4 flag-bytes per uint)
  __shared__ float rs_lds[8][16];          // per-wave row-sum partials
  __shared__ float acc_red[4][16][17];     // PV partial exchange
  __shared__ float inv_row[16];            // 1/rowsum per l-row (for stores)

  const int n = blockIdx.y;
  const int l0 = blockIdx.x * 16;

  const int t = threadIdx.x;
  const int w = t >> 6;
  const int lane = t & 63;
  const int m16 = lane & 15;
  const int quad = lane >> 4;
  const int vg = w & 3;            // PV v-group
  const int sh = (w >> 2) * 64;    // PV s-half within chunk

  // Q fragment (B operand of transposed QK): B[n=m16][k=quad*8+j] = Q[l0+m16][k]
  const __bf16* qrow = Qb + ((size_t)(n * LL + l0 + m16)) * DD;
  bf16x8 aq0 = *(const bf16x8*)(qrow + quad * 8);
  bf16x8 aq1 = *(const bf16x8*)(qrow + 32 + quad * 8);

  const __bf16* kbase = Kb + (size_t)n * SS * DD;
  const __bf16* krow0 = kbase + (size_t)(w * 16 + m16) * DD;
  const __bf16* vrow = Vt + ((size_t)(n * DD + vg * 16 + m16)) * SS + sh;

  // coalesced mask staging coords: thread t -> row t>>5, cols (t&31)*4..+4
  const int mrow_st = t >> 5;
  const int* mgbase = mask + ((size_t)(n * LL + l0 + mrow_st)) * SS + (t & 31) * 4;

  // ================= phase 1: rowsum + mask-bit packing =================
  float rsum = 0.f;
  unsigned mbits0 = 0, mbits1 = 0;  // 4 bits per chunk, 16 chunks

  int4 mreg[2];
  mreg[0] = *(const int4*)(mgbase + 0 * 128);
  mreg[1] = *(const int4*)(mgbase + 1 * 128);

  bf16x8 kpa0, kpa1, kpb0, kpb1;
  kpa0 = *(const bf16x8*)(krow0 + quad * 8);
  kpa1 = *(const bf16x8*)(krow0 + 32 + quad * 8);

  {  // prologue: stage m(0) into LDS buf 0
    const int4 m = mreg[0];
    mb_lds[0][mrow_st][t & 31] = (unsigned)((m.x != 0) | ((m.y != 0) << 8) |
                                            ((m.z != 0) << 16) | ((m.w != 0) << 24));
  }
  asm volatile("s_waitcnt lgkmcnt(0)" ::: "memory");
  __builtin_amdgcn_s_barrier();

#pragma unroll
  for (int c = 0; c < 16; ++c) {
    // K for chunk c+1 (consumed next chunk)
    if (c + 1 < 16) {
      const __bf16* kr = krow0 + (size_t)((c + 1) * 128) * DD;
      if (c & 1) {
        kpa0 = *(const bf16x8*)(kr + quad * 8);
        kpa1 = *(const bf16x8*)(kr + 32 + quad * 8);
      } else {
        kpb0 = *(const bf16x8*)(kr + quad * 8);
        kpb1 = *(const bf16x8*)(kr + 32 + quad * 8);
      }
    }
    // mask(c+2) global -> reg (coalesced 512B runs)
    if (c + 2 < 16) mreg[c & 1] = *(const int4*)(mgbase + (size_t)(c + 2) * 128);
    // stage m(c+1) reg -> LDS
    if (c + 1 < 16) {
      const int4 m = mreg[(c + 1) & 1];
      mb_lds[(c + 1) & 1][mrow_st][t & 31] =
          (unsigned)((m.x != 0) | ((m.y != 0) << 8) | ((m.z != 0) << 16) |
                     ((m.w != 0) << 24));
    }
    // this chunk's flags for the owner lane
    const unsigned mu = mb_lds[c & 1][m16][w * 4 + quad];
    const bf16x8 kb0 = (c & 1) ? kpb0 : kpa0;
    const bf16x8 kb1 = (c & 1) ? kpb1 : kpa1;
    f32x4 acc = {0.f, 0.f, 0.f, 0.f};
    acc = __builtin_amdgcn_mfma_f32_16x16x32_bf16(kb0, aq0, acc, 0, 0, 0);
    acc = __builtin_amdgcn_mfma_f32_16x16x32_bf16(kb1, aq1, acc, 0, 0, 0);
    rsum += ((mu & 0x1u) ? __expf(acc[0]) : 0.f) +
            ((mu & 0x100u) ? __expf(acc[1]) : 0.f) +
            ((mu & 0x10000u) ? __expf(acc[2]) : 0.f) +
            ((mu & 0x1000000u) ? __expf(acc[3]) : 0.f);
    // pack 4 flag bits for phase 2 (bytes -> bits)
    const unsigned b4 = (mu & 1u) | ((mu >> 7) & 2u) | ((mu >> 14) & 4u) |
                        ((mu >> 21) & 8u);
    if (c < 8) mbits0 |= b4 << (c * 4);
    else mbits1 |= b4 << ((c - 8) * 4);
    // LDS-only fence + barrier (mb_lds dbuf ordering; globals stay in flight)
    asm volatile("s_waitcnt lgkmcnt(0)" ::: "memory");
    __builtin_amdgcn_s_barrier();
  }

  // rowsum reduce: quads -> wave partial -> cross-wave total
  rsum += __shfl_xor(rsum, 16);
  rsum += __shfl_xor(rsum, 32);
  if (quad == 0) rs_lds[w][m16] = rsum;
  __syncthreads();
  float tot = 0.f;
#pragma unroll
  for (int ww = 0; ww < 8; ++ww) tot += rs_lds[ww][m16];
  const float inv_s = 1.0f / tot;  // row l = l0+m16
  if (t < 16) inv_row[t] = inv_s;  // t<16 -> w=0, m16=t; ordered by chunk-0 barrier

  // ================= phase 2: recompute + PV + streamed stores =================
  f32x4 acc_o = {0.f, 0.f, 0.f, 0.f};
  kpa0 = *(const bf16x8*)(krow0 + quad * 8);
  kpa1 = *(const bf16x8*)(krow0 + 32 + quad * 8);
  bf16x8 bva0, bva1, bvb0, bvb1;  // Vt dbuf: bv(c) loaded at chunk c-1
  bva0 = *(const bf16x8*)(vrow + quad * 8);
  bva1 = *(const bf16x8*)(vrow + 32 + quad * 8);

  const int erow = t >> 5;          // store coords: 32 threads per l-row
  const int ecol = (t & 31) * 4;
  float* obase = out_score + ((size_t)(n * LL + l0 + erow)) * SS + ecol;

#pragma unroll
  for (int c = 0; c < 16; ++c) {
    const int sc = c * 128;
    // issue next chunk's K then bv (consumption order: QK before PV)
    if (c + 1 < 16) {
      const __bf16* kr = krow0 + (size_t)(sc + 128) * DD;
      const __bf16* vr = vrow + sc + 128;
      if (c & 1) {
        kpa0 = *(const bf16x8*)(kr + quad * 8);
        kpa1 = *(const bf16x8*)(kr + 32 + quad * 8);
        bva0 = *(const bf16x8*)(vr + quad * 8);
        bva1 = *(const bf16x8*)(vr + 32 + quad * 8);
      } else {
        kpb0 = *(const bf16x8*)(kr + quad * 8);
        kpb1 = *(const bf16x8*)(kr + 32 + quad * 8);
        bvb0 = *(const bf16x8*)(vr + quad * 8);
        bvb1 = *(const bf16x8*)(vr + 32 + quad * 8);
      }
    }
    const bf16x8 kb0 = (c & 1) ? kpb0 : kpa0;
    const bf16x8 kb1 = (c & 1) ? kpb1 : kpa1;
    const bf16x8 bv0 = (c & 1) ? bvb0 : bva0;
    const bf16x8 bv1 = (c & 1) ? bvb1 : bva1;
    // QK transposed (recompute; deterministic)
    f32x4 acc = {0.f, 0.f, 0.f, 0.f};
    acc = __builtin_amdgcn_mfma_f32_16x16x32_bf16(kb0, aq0, acc, 0, 0, 0);
    acc = __builtin_amdgcn_mfma_f32_16x16x32_bf16(kb1, aq1, acc, 0, 0, 0);
    const unsigned b4 =
        ((c < 8 ? mbits0 >> (c * 4) : mbits1 >> ((c - 8) * 4))) & 0xFu;
    const float e0 = (b4 & 1u) ? __expf(acc[0]) : 0.f;
    const float e1 = (b4 & 2u) ? __expf(acc[1]) : 0.f;
    const float e2 = (b4 & 4u) ? __expf(acc[2]) : 0.f;
    const float e3 = (b4 & 8u) ? __expf(acc[3]) : 0.f;
    bf16x4 sv;
    sv[0] = (__bf16)e0;
    sv[1] = (__bf16)e1;
    sv[2] = (__bf16)e2;
    sv[3] = (__bf16)e3;
    *(bf16x4*)(&e_lds[c & 1][m16][w * 16 + quad * 4]) = sv;
    asm volatile("s_waitcnt lgkmcnt(0)" ::: "memory");
    __builtin_amdgcn_s_barrier();
    // PV: A = E[l][s-half] from LDS, B = Vt regs (prefetched last chunk)
    bf16x8 ae0 = *(const bf16x8*)(&e_lds[c & 1][m16][sh + quad * 8]);
    bf16x8 ae1 = *(const bf16x8*)(&e_lds[c & 1][m16][sh + 32 + quad * 8]);
    acc_o = __builtin_amdgcn_mfma_f32_16x16x32_bf16(ae0, bv0, acc_o, 0, 0, 0);
    acc_o = __builtin_amdgcn_mfma_f32_16x16x32_bf16(ae1, bv1, acc_o, 0, 0, 0);
    // streamed normalized score store straight from e_lds:
    // thread t -> row t>>5, cols (t&31)*4 — 32 lanes = 512B contiguous run.
    {
      const bf16x4 ev = *(const bf16x4*)(&e_lds[c & 1][erow][ecol]);
      const float ei = inv_row[erow];
      float4 o;
      o.x = (float)ev[0] * ei;
      o.y = (float)ev[1] * ei;
      o.z = (float)ev[2] * ei;
      o.w = (float)ev[3] * ei;
      *(float4*)(obase + sc) = o;
    }
    // dbuf proof: e_lds[c&1] (PV + store reads, pre-barrier-c+1) next written
    // at chunk c+2, which is after barrier c+1. Race-free.
  }

  // ---- out_value: combine s-half pair partials (as r8) ----
  rsum = 0.f;  // reuse: nothing to do; rs_lds survives phase 2
  if (w >= 4) {
#pragma unroll
    for (int r = 0; r < 4; ++r) acc_red[vg][quad * 4 + r][m16] = acc_o[r];
  }
  __syncthreads();
  if (w < 4) {
#pragma unroll
    for (int r = 0; r < 4; ++r) {
      const int row = quad * 4 + r;
      float tr = 0.f;
#pragma unroll
      for (int ww = 0; ww < 8; ++ww) tr += rs_lds[ww][row];
      const float o = (acc_o[r] + acc_red[vg][row][m16]) / tr;
      out_val[((size_t)(n * LL + l0 + row)) * DD + vg * 16 + m16] = o;
    }
  }
}

extern "C" void kernel_launch(void* const* d_in, const int* in_sizes, int n_in,
                              void* d_out, int out_size, void* d_ws, size_t ws_size,
                              hipStream_t stream) {
  const float* q = (const float*)d_in[0];
  const float* k = (const float*)d_in[1];
  const float* v = (const float*)d_in[2];
  const int* mask = (const int*)d_in[3];  // harness materializes bool as int32

  float* out_val = (float*)d_out;                       // [8,2048,64]
  float* out_score = out_val + (size_t)NB * LL * DD;    // [8,2048,2048]

  __bf16* Qb = (__bf16*)d_ws;                  // 2 MB
  __bf16* Kb = Qb + (size_t)NB * LL * DD;      // 2 MB
  __bf16* Vt = Kb + (size_t)NB * SS * DD;      // 2 MB (transposed [n][v][s])

  prep_norm<<<dim3((NB * LL * 2) / 4), dim3(256), 0, stream>>>(q, k, Qb, Kb);
  prep_vt<<<dim3(SS / 64, NB), dim3(256), 0, stream>>>(v, Vt);
  attn_main<<<dim3(LL / 16, NB), dim3(512), 0, stream>>>(Qb, Kb, Vt, mask, out_val, out_score);
}

// Round 10
// 280.680 us; speedup vs baseline: 1.0844x; 1.0844x over previous
//
#include <hip/hip_runtime.h>
#include <hip/hip_bf16.h>
#include <math.h>

// Cosine attention, n=8, L=S=2048, d=v=64.
// out0 = softmax((q^·k^T)/8) @ V  [8,2048,64]; out1 = softmax scores [8,2048,2048]
// |score| <= 1/8 (unit vectors) -> exp in [0.88,1.13] -> no running max needed.
//
// v10 = r8 (best: 99us attn / 278 total) + deeper prefetch + LDS overlay.
//   Ledger: every structural departure from this single-pass shape regressed
//   (r2 reg-PV 172, r5 two-phase 137, r6 pinning+order-bug 130, r9 two-phase
//   127); both wins were memory fixes inside it (r3 mask latency, r8
//   transaction coalescing). This round fixes r8's one identified stall:
//   the mask reg->LDS stage waited on a global load issued only ONE chunk
//   earlier (~400cy cover vs ~900cy HBM miss; FETCH 83MB = mask misses).
//   1. mask register ring depth 4: load m(c+4) at chunk c, stage m(c+1)
//      from a reg loaded 3 chunks ago (~1200cy cover >= HBM latency).
//   2. bv (Vt) double-buffer: bv(c+1) loaded at chunk c, consumed after
//      barrier c+1. In-chunk issue order = consumption order (K, bv, mask)
//      so no vmcnt wait drains a younger prefetch (r7 lesson).
//   3. ep_buf overlaid on dead main-loop LDS (34.8KB -> 17.9KB/block).
//   Keep: transposed QK, LDS E-exchange full-rate 16x16x32 PV, coalesced
//   LDS mask staging, stash + coalesced transposed epilogue, lgkm-only
//   barriers, unpinned grid, 3-kernel prep.
// Mask arrives as int32 (harness materializes bool as int) — NOT bytes.

typedef __bf16 bf16x8 __attribute__((ext_vector_type(8)));
typedef __bf16 bf16x4 __attribute__((ext_vector_type(4)));
typedef float f32x4 __attribute__((ext_vector_type(4)));

#define NB 8
#define LL 2048
#define SS 2048
#define DD 64

// ---- prep 1: L2-normalize Q (fold 1/8) and K rows, cast to bf16 ----
__global__ __launch_bounds__(256) void prep_norm(const float* __restrict__ q,
                                                 const float* __restrict__ k,
                                                 __bf16* __restrict__ Qb,
                                                 __bf16* __restrict__ Kb) {
  int w = threadIdx.x >> 6, lane = threadIdx.x & 63;
  int r = blockIdx.x * 4 + w;
  const float* src;
  __bf16* dst;
  float extra;
  if (r < NB * LL) {
    src = q + (size_t)r * DD;
    dst = Qb + (size_t)r * DD;
    extra = 0.125f;  // fold 1/sqrt(64) into Q
  } else {
    int rk = r - NB * LL;
    src = k + (size_t)rk * DD;
    dst = Kb + (size_t)rk * DD;
    extra = 1.0f;
  }
  float x = src[lane];
  float ss = x * x;
  ss += __shfl_xor(ss, 1);
  ss += __shfl_xor(ss, 2);
  ss += __shfl_xor(ss, 4);
  ss += __shfl_xor(ss, 8);
  ss += __shfl_xor(ss, 16);
  ss += __shfl_xor(ss, 32);
  float nrm = sqrtf(ss);
  float sc = extra / fmaxf(nrm, 1e-12f);
  dst[lane] = (__bf16)(x * sc);
}

// ---- prep 2: V [n][s][v] f32 -> Vt [n][v][s] bf16 (64x64 LDS tiles) ----
__global__ __launch_bounds__(256) void prep_vt(const float* __restrict__ v,
                                               __bf16* __restrict__ Vt) {
  __shared__ __bf16 tile[64][72];
  int n = blockIdx.y;
  int s0 = blockIdx.x * 64;
  int t = threadIdx.x;
#pragma unroll
  for (int it = 0; it < 4; ++it) {
    int idx = t + it * 256;
    int s = idx >> 4, c = idx & 15;
    float4 f = *(const float4*)(v + ((size_t)(n * SS + s0 + s)) * DD + c * 4);
    tile[s][c * 4 + 0] = (__bf16)f.x;
    tile[s][c * 4 + 1] = (__bf16)f.y;
    tile[s][c * 4 + 2] = (__bf16)f.z;
    tile[s][c * 4 + 3] = (__bf16)f.w;
  }
  __syncthreads();
#pragma unroll
  for (int it = 0; it < 4; ++it) {
    int idx = t + it * 256;
    int vv = idx >> 4, c = idx & 15;
    bf16x4 o;
    o[0] = tile[c * 4 + 0][vv];
    o[1] = tile[c * 4 + 1][vv];
    o[2] = tile[c * 4 + 2][vv];
    o[3] = tile[c * 4 + 3][vv];
    *(bf16x4*)(Vt + ((size_t)(n * DD + vv)) * SS + s0 + c * 4) = o;
  }
}

// ---- main: 16 L-rows per block, 8 waves (512 thr), S streamed in 128-col chunks ----
// Wave w: QK for s-cols [w*16, w*16+16) of each chunk (transposed D[s][l]);
// PV split by (v-group = w&3, s-half = (w>>2)*64).
// LDS overlay (bytes):
//   [0,8704)      e_lds   [2][16][136] bf16      } dead after main loop
//   [8704,12928)  mb_lds  [2][16][33]  unsigned  }
//   [12928,13440) rs_lds  [8][16]      float     } dead after out_val
//   [13440,17792) acc_red [4][16][17]  float     }
//   [17792,17856) inv_row [16]         float     live through epilogue
//   epilogue: ep_buf [16][520] bf16 = 16640 B aliases [0,16640)
__global__ __launch_bounds__(512, 4) void attn_main(const __bf16* __restrict__ Qb,
                                                    const __bf16* __restrict__ Kb,
                                                    const __bf16* __restrict__ Vt,
                                                    const int* __restrict__ mask,
                                                    float* __restrict__ out_val,
                                                    float* __restrict__ out_score) {
  __shared__ __align__(16) char smem[17856];
  __bf16 (*e_lds)[16][136] = (__bf16(*)[16][136])(smem);
  unsigned (*mb_lds)[16][33] = (unsigned(*)[16][33])(smem + 8704);
  float (*rs_lds)[16] = (float(*)[16])(smem + 12928);
  float (*acc_red)[16][17] = (float(*)[16][17])(smem + 13440);
  float* inv_row = (float*)(smem + 17792);
  __bf16 (*ep_buf)[520] = (__bf16(*)[520])(smem);

  const int n = blockIdx.y;
  const int l0 = blockIdx.x * 16;

  const int t = threadIdx.x;
  const int w = t >> 6;
  const int lane = t & 63;
  const int m16 = lane & 15;
  const int quad = lane >> 4;
  const int vg = w & 3;            // PV v-group
  const int sh = (w >> 2) * 64;    // PV s-half within chunk

  // Q fragment (B operand of transposed QK): B[n=m16][k=quad*8+j] = Q[l0+m16][k]
  const __bf16* qrow = Qb + ((size_t)(n * LL + l0 + m16)) * DD;
  bf16x8 aq0 = *(const bf16x8*)(qrow + quad * 8);
  bf16x8 aq1 = *(const bf16x8*)(qrow + 32 + quad * 8);

  const __bf16* kbase = Kb + (size_t)n * SS * DD;
  const __bf16* krow0 = kbase + (size_t)(w * 16 + m16) * DD;
  const __bf16* vrow = Vt + ((size_t)(n * DD + vg * 16 + m16)) * SS + sh;

  // coalesced mask staging coords: thread t -> row t>>5, cols (t&31)*4..+4
  const int mrow_st = t >> 5;
  const int* mgbase = mask + ((size_t)(n * LL + l0 + mrow_st)) * SS + (t & 31) * 4;

  f32x4 acc_o = {0.f, 0.f, 0.f, 0.f};
  float rsum = 0.f;
  bf16x4 stash[16];  // exp'd scores, 4 consecutive s per chunk (static idx -> regs)

  // mask register ring, depth 4: slot x holds m(c) with c === x (mod 4).
  // At chunk c: stage m(c+1) (loaded at chunk c-3), load m(c+4) into slot c&3.
  int4 mreg[4];
  mreg[0] = *(const int4*)(mgbase + 0 * 128);
  mreg[1] = *(const int4*)(mgbase + 1 * 128);
  mreg[2] = *(const int4*)(mgbase + 2 * 128);
  mreg[3] = *(const int4*)(mgbase + 3 * 128);

  // K fragment ping-pong
  bf16x8 kpa0, kpa1, kpb0, kpb1;
  kpa0 = *(const bf16x8*)(krow0 + quad * 8);
  kpa1 = *(const bf16x8*)(krow0 + 32 + quad * 8);
  // bv (Vt) double buffer: bv(c) loaded at chunk c-1
  bf16x8 bva0, bva1, bvb0, bvb1;
  bva0 = *(const bf16x8*)(vrow + quad * 8);
  bva1 = *(const bf16x8*)(vrow + 32 + quad * 8);

  {  // prologue: stage m(0) into LDS buf 0
    const int4 m = mreg[0];
    mb_lds[0][mrow_st][t & 31] = (unsigned)((m.x != 0) | ((m.y != 0) << 8) |
                                            ((m.z != 0) << 16) | ((m.w != 0) << 24));
  }
  asm volatile("s_waitcnt lgkmcnt(0)" ::: "memory");
  __builtin_amdgcn_s_barrier();

#pragma unroll
  for (int c = 0; c < 16; ++c) {
    const int sc = c * 128;
    // ---- global prefetch, issue order = consumption order ----
    // (1) K(c+1): consumed at chunk c+1's QK (pre-barrier)
    if (c + 1 < 16) {
      const __bf16* kr = krow0 + (size_t)(sc + 128) * DD;
      if (c & 1) {
        kpa0 = *(const bf16x8*)(kr + quad * 8);
        kpa1 = *(const bf16x8*)(kr + 32 + quad * 8);
      } else {
        kpb0 = *(const bf16x8*)(kr + quad * 8);
        kpb1 = *(const bf16x8*)(kr + 32 + quad * 8);
      }
    }
    // (2) bv(c+1): consumed at chunk c+1's PV (post-barrier)
    if (c + 1 < 16) {
      const __bf16* vr = vrow + sc + 128;
      if (c & 1) {
        bva0 = *(const bf16x8*)(vr + quad * 8);
        bva1 = *(const bf16x8*)(vr + 32 + quad * 8);
      } else {
        bvb0 = *(const bf16x8*)(vr + quad * 8);
        bvb1 = *(const bf16x8*)(vr + 32 + quad * 8);
      }
    }
    // (3) mask m(c+4): consumed (staged) at chunk c+3 — farthest, issued last
    if (c + 4 < 16) mreg[c & 3] = *(const int4*)(mgbase + (size_t)(c + 4) * 128);
    // stage m(c+1) reg -> LDS (loaded at chunk c-3: ~3 chunks of latency cover)
    if (c + 1 < 16) {
      const int4 m = mreg[(c + 1) & 3];
      mb_lds[(c + 1) & 1][mrow_st][t & 31] =
          (unsigned)((m.x != 0) | ((m.y != 0) << 8) | ((m.z != 0) << 16) |
                     ((m.w != 0) << 24));
    }
    // this chunk's flags for the owner lane: one uint = 4 flag bytes
    const unsigned mu = mb_lds[c & 1][m16][w * 4 + quad];
    // QK transposed: D[row=quad*4+r -> s][col=m16 -> l]
    const bf16x8 kb0 = (c & 1) ? kpb0 : kpa0;
    const bf16x8 kb1 = (c & 1) ? kpb1 : kpa1;
    const bf16x8 bv0 = (c & 1) ? bvb0 : bva0;
    const bf16x8 bv1 = (c & 1) ? bvb1 : bva1;
    f32x4 acc = {0.f, 0.f, 0.f, 0.f};
    acc = __builtin_amdgcn_mfma_f32_16x16x32_bf16(kb0, aq0, acc, 0, 0, 0);
    acc = __builtin_amdgcn_mfma_f32_16x16x32_bf16(kb1, aq1, acc, 0, 0, 0);
    float e0 = (mu & 0x1u) ? __expf(acc[0]) : 0.f;
    float e1 = (mu & 0x100u) ? __expf(acc[1]) : 0.f;
    float e2 = (mu & 0x10000u) ? __expf(acc[2]) : 0.f;
    float e3 = (mu & 0x1000000u) ? __expf(acc[3]) : 0.f;
    rsum += (e0 + e1) + (e2 + e3);
    bf16x4 sv;
    sv[0] = (__bf16)e0;
    sv[1] = (__bf16)e1;
    sv[2] = (__bf16)e2;
    sv[3] = (__bf16)e3;
    stash[c] = sv;
    *(bf16x4*)(&e_lds[c & 1][m16][w * 16 + quad * 4]) = sv;
    // LDS-only fence + raw barrier (orders e_lds AND mb_lds; global prefetches
    // stay in flight — no vmcnt(0)).
    asm volatile("s_waitcnt lgkmcnt(0)" ::: "memory");
    __builtin_amdgcn_s_barrier();
    // PV: A = E[l][s-half] from LDS, B = Vt regs (prefetched last chunk)
    bf16x8 ae0 = *(const bf16x8*)(&e_lds[c & 1][m16][sh + quad * 8]);
    bf16x8 ae1 = *(const bf16x8*)(&e_lds[c & 1][m16][sh + 32 + quad * 8]);
    acc_o = __builtin_amdgcn_mfma_f32_16x16x32_bf16(ae0, bv0, acc_o, 0, 0, 0);
    acc_o = __builtin_amdgcn_mfma_f32_16x16x32_bf16(ae1, bv1, acc_o, 0, 0, 0);
    // dbuf proofs: e_lds[c&1]/mb_lds[(c+1)&1] rewritten only after the barrier
    // following their last reads; mreg slot c&3 freed by the stage at c-1.
  }

  // rowsum: reduce quads within wave, publish, combine across waves
  rsum += __shfl_xor(rsum, 16);
  rsum += __shfl_xor(rsum, 32);
  if (quad == 0) rs_lds[w][m16] = rsum;
  if (w >= 4) {
#pragma unroll
    for (int r = 0; r < 4; ++r) acc_red[vg][quad * 4 + r][m16] = acc_o[r];
  }
  __syncthreads();

  float tot = 0.f;
#pragma unroll
  for (int ww = 0; ww < 8; ++ww) tot += rs_lds[ww][m16];
  const float inv_s = 1.0f / tot;  // row l = l0+m16
  if (t < 16) inv_row[t] = inv_s;  // t<16 -> w=0, m16=t

  // out_value: lower s-half waves combine pair partials
  if (w < 4) {
#pragma unroll
    for (int r = 0; r < 4; ++r) {
      const int row = quad * 4 + r;
      float tr = 0.f;
#pragma unroll
      for (int ww = 0; ww < 8; ++ww) tr += rs_lds[ww][row];
      const float o = (acc_o[r] + acc_red[vg][row][m16]) / tr;
      out_val[((size_t)(n * LL + l0 + row)) * DD + vg * 16 + m16] = o;
    }
  }
  __syncthreads();  // inv_row visible; rs/acc_red dead -> ep_buf may alias

  // ---- score epilogue: LDS transpose -> fully coalesced stores ----
  // 4 groups of 512 s-cols; store thread t -> row t>>5, col (t&31)*4 + i*128:
  // 32 consecutive lanes write 512B contiguous per instruction.
  const int erow = t >> 5;
  const int ecol = (t & 31) * 4;
  const float einv = inv_row[erow];
  float* obase = out_score + ((size_t)(n * LL + l0 + erow)) * SS;
#pragma unroll
  for (int g = 0; g < 4; ++g) {
#pragma unroll
    for (int i = 0; i < 4; ++i) {
      *(bf16x4*)(&ep_buf[m16][i * 128 + w * 16 + quad * 4]) = stash[g * 4 + i];
    }
    asm volatile("s_waitcnt lgkmcnt(0)" ::: "memory");
    __builtin_amdgcn_s_barrier();
#pragma unroll
    for (int i = 0; i < 4; ++i) {
      const bf16x4 ev = *(const bf16x4*)(&ep_buf[erow][ecol + i * 128]);
      float4 o;
      o.x = (float)ev[0] * einv;
      o.y = (float)ev[1] * einv;
      o.z = (float)ev[2] * einv;
      o.w = (float)ev[3] * einv;
      *(float4*)(obase + g * 512 + ecol + i * 128) = o;
    }
    asm volatile("s_waitcnt lgkmcnt(0)" ::: "memory");
    __builtin_amdgcn_s_barrier();  // reads done before next group's writes
  }
}

extern "C" void kernel_launch(void* const* d_in, const int* in_sizes, int n_in,
                              void* d_out, int out_size, void* d_ws, size_t ws_size,
                              hipStream_t stream) {
  const float* q = (const float*)d_in[0];
  const float* k = (const float*)d_in[1];
  const float* v = (const float*)d_in[2];
  const int* mask = (const int*)d_in[3];  // harness materializes bool as int32

  float* out_val = (float*)d_out;                       // [8,2048,64]
  float* out_score = out_val + (size_t)NB * LL * DD;    // [8,2048,2048]

  __bf16* Qb = (__bf16*)d_ws;                  // 2 MB
  __bf16* Kb = Qb + (size_t)NB * LL * DD;      // 2 MB
  __bf16* Vt = Kb + (size_t)NB * SS * DD;      // 2 MB (transposed [n][v][s])

  prep_norm<<<dim3((NB * LL * 2) / 4), dim3(256), 0, stream>>>(q, k, Qb, Kb);
  prep_vt<<<dim3(SS / 64, NB), dim3(256), 0, stream>>>(v, Vt);
  attn_main<<<dim3(LL / 16, NB), dim3(512), 0, stream>>>(Qb, Kb, Vt, mask, out_val, out_score);
}